// Round 18
// baseline (152.321 us; speedup 1.0000x reference)
//
#include <hip/hip_runtime.h>
#include <hip/hip_bf16.h>
#include <stdint.h>

typedef unsigned short u16;
typedef __attribute__((ext_vector_type(8))) short bf16x8;
typedef __attribute__((ext_vector_type(4))) float f32x4;

#define LDS_AS(p) ((__attribute__((address_space(3))) void*)(p))
#define GLB_AS(p) ((__attribute__((address_space(1))) void*)(p))

__device__ __forceinline__ u16 f2bf(float f) {
  union { float f; uint32_t u; } v; v.f = f;
  uint32_t u = v.u;
  u += 0x7fffu + ((u >> 16) & 1u);
  return (u16)(u >> 16);
}

__device__ __forceinline__ float exp2_fast(float x) {  // 2^x via v_exp_f32
  float r;
  asm("v_exp_f32 %0, %1" : "=v"(r) : "v"(x));
  return r;
}

__device__ __forceinline__ uint32_t f2bits(float f) {
  union { float f; uint32_t u; } v; v.f = f; return v.u;
}
// dst = (hi16 of hi_src) << 16 | (hi16 of lo_src)  -- one v_perm_b32
__device__ __forceinline__ uint32_t pack_hi16(uint32_t lo_src, uint32_t hi_src) {
  return __builtin_amdgcn_perm(hi_src, lo_src, 0x07060302u);
}

// ---------------- fp32 -> bf16 conversion ----------------
__device__ __forceinline__ void cvt8(const float* __restrict__ s, u16* __restrict__ d) {
  const float4* sv = (const float4*)s;
  float4 a = sv[0], b = sv[1];
  uint4 o;
  o.x = (uint32_t)f2bf(a.x) | ((uint32_t)f2bf(a.y) << 16);
  o.y = (uint32_t)f2bf(a.z) | ((uint32_t)f2bf(a.w) << 16);
  o.z = (uint32_t)f2bf(b.x) | ((uint32_t)f2bf(b.y) << 16);
  o.w = (uint32_t)f2bf(b.z) | ((uint32_t)f2bf(b.w) << 16);
  *(uint4*)d = o;
}

__global__ __launch_bounds__(256) void k_convert(
    const float* __restrict__ x, const float* __restrict__ wq, const float* __restrict__ wp,
    u16* __restrict__ xb, u16* __restrict__ wqb, u16* __restrict__ wpb) {
  int tid = blockIdx.x * 256 + threadIdx.x;
  int np  = gridDim.x * 256;
  for (int i = tid; i < (8192*768)/8; i += np) cvt8(x  + (size_t)i*8, xb  + (size_t)i*8);
  for (int i = tid; i < (2304*768)/8; i += np) cvt8(wq + (size_t)i*8, wqb + (size_t)i*8);
  for (int i = tid; i < (768*768)/8;  i += np) cvt8(wp + (size_t)i*8, wpb + (size_t)i*8);
}

// ---------------- shared 128x128 bf16 GEMM mainloop, 3-buffer distance-2 pipeline ----------------
// Ledger (R10-proven pattern): 4 global_load_lds/thread/tile; prologue stages tiles 0,1.
// Iter kt: vmcnt(4) [tile kt landed; kt+1 may fly] -> s_barrier [block-wide complete;
// buf[(kt+2)%3] free: its readers (compute kt-1) finished before this barrier] ->
// stage(kt+2) -> compute(kt). Loads get ~2 compute phases to land.
// SWAP=false: acc rows = A-rows (tokens), cols = B-rows (feats); SWAP=true: transposed.
template<bool SWAP>
__device__ __forceinline__ void gemm_core(const u16* __restrict__ A,
                                          const u16* __restrict__ B,
                                          u16* As, u16* Bs,   // each [3][128*32]
                                          int rowA0, int rowB0,
                                          f32x4 acc[4][4]) {
  const int t  = threadIdx.x;
  const int lane = t & 63;
  const int wv = t >> 6;
  const int wr = wv >> 1, wc = wv & 1;
  const int lr = lane & 15, lg = lane >> 4;

#define GSTAGE(KT, BUF)                                                                         \
  {                                                                                             \
    _Pragma("unroll")                                                                           \
    for (int p = 0; p < 2; ++p) {                                                               \
      int idx = p * 256 + t;                                                                    \
      int row = idx >> 2;                                                                       \
      int cc  = (idx & 3) ^ ((row >> 1) & 3);                                                   \
      __builtin_amdgcn_global_load_lds(GLB_AS(A + (size_t)(rowA0 + row) * 768 + (KT) * 32 + cc * 8), \
                                       LDS_AS(As + (BUF) * 4096 + idx * 8), 16, 0, 0);          \
    }                                                                                           \
    _Pragma("unroll")                                                                           \
    for (int p = 0; p < 2; ++p) {                                                               \
      int idx = p * 256 + t;                                                                    \
      int row = idx >> 2;                                                                       \
      int cc  = (idx & 3) ^ ((row >> 1) & 3);                                                   \
      __builtin_amdgcn_global_load_lds(GLB_AS(B + (size_t)(rowB0 + row) * 768 + (KT) * 32 + cc * 8), \
                                       LDS_AS(Bs + (BUF) * 4096 + idx * 8), 16, 0, 0);          \
    }                                                                                           \
  }

  GSTAGE(0, 0);   // 4 outstanding
  GSTAGE(1, 1);   // 8 outstanding

  int cur = 0, stg = 2;
#pragma unroll 1
  for (int kt = 0; kt < 24; ++kt) {
    if (kt < 23) {
      asm volatile("s_waitcnt vmcnt(4)" ::: "memory");
    } else {
      asm volatile("s_waitcnt vmcnt(0)" ::: "memory");
    }
    __builtin_amdgcn_sched_barrier(0);
    __builtin_amdgcn_s_barrier();           // tile kt block-wide complete; buf[stg] free
    __builtin_amdgcn_sched_barrier(0);

    if (kt < 22) GSTAGE(kt + 2, stg);       // lands during the next ~2 compute phases

    const u16* Ab = As + cur * 4096;
    const u16* Bb = Bs + cur * 4096;
    bf16x8 af[4], bf_[4];
#pragma unroll
    for (int mi = 0; mi < 4; ++mi) {
      int row = wr * 64 + mi * 16 + lr;
      int cc  = lg ^ ((row >> 1) & 3);
      af[mi] = *(const bf16x8*)(Ab + row * 32 + cc * 8);
    }
#pragma unroll
    for (int ni = 0; ni < 4; ++ni) {
      int row = wc * 64 + ni * 16 + lr;
      int cc  = lg ^ ((row >> 1) & 3);
      bf_[ni] = *(const bf16x8*)(Bb + row * 32 + cc * 8);
    }
#pragma unroll
    for (int mi = 0; mi < 4; ++mi)
#pragma unroll
      for (int ni = 0; ni < 4; ++ni) {
        if (SWAP)
          acc[mi][ni] = __builtin_amdgcn_mfma_f32_16x16x32_bf16(bf_[ni], af[mi], acc[mi][ni], 0, 0, 0);
        else
          acc[mi][ni] = __builtin_amdgcn_mfma_f32_16x16x32_bf16(af[mi], bf_[ni], acc[mi][ni], 0, 0, 0);
      }

    cur = (cur == 2) ? 0 : cur + 1;
    stg = (stg == 2) ? 0 : stg + 1;
  }
#undef GSTAGE
}

// ---------------- GEMM1: qkv projection + scatter into Qhat/Khat/Vt, all-packed stores ----------------
// C1 = 0.4*log2(e) folded into sc1/sc2 so attn's softmax uses exp2(acc) directly.
__global__ __launch_bounds__(256) void k_gemm_qkv(
    const u16* __restrict__ Aq, const u16* __restrict__ Bw, const float* __restrict__ bias,
    u16* __restrict__ Qh, u16* __restrict__ Kh, u16* __restrict__ Vt) {
  __shared__ u16 As[3 * 128 * 32];
  __shared__ u16 Bs[3 * 128 * 32];
  int bid = blockIdx.x;
  int wg  = (bid & 7) * 144 + (bid >> 3);
  int bx  = wg % 18, by = wg / 18;

  const int t = threadIdx.x, lane = t & 63, wv = t >> 6;
  const int wr = wv >> 1, wc = wv & 1, lr = lane & 15, lg = lane >> 4;
  const int tsec = bx / 6;            // 0=q, 1=k, 2=v (uniform per block)
  const int colBase = bx * 128 + wc * 64;

  const float gam = 0.7905694150420949f;
  const float rC1 = __builtin_sqrtf(0.57707801636f);    // sqrt(0.4*log2e)
  const float sc1 = __builtin_sqrtf(0.09375f / gam) * rC1;
  const float sc2 = __builtin_sqrtf(0.03125f / gam) * rC1;

  f32x4 acc[4][4];
#pragma unroll
  for (int mi = 0; mi < 4; ++mi)
#pragma unroll
    for (int ni = 0; ni < 4; ++ni) acc[mi][ni] = (f32x4){0.f, 0.f, 0.f, 0.f};

  if (tsec < 2) {
    // ---- swapped orientation: lane holds 4 consecutive feats at one token ----
    gemm_core<true>(Aq, Bw, As, Bs, by * 128, bx * 128, acc);

    float4 bv4[4];
#pragma unroll
    for (int ni = 0; ni < 4; ++ni)
      bv4[ni] = *(const float4*)(bias + colBase + ni * 16 + lg * 4);

#pragma unroll
    for (int mi = 0; mi < 4; ++mi) {
      int n = by * 128 + wr * 64 + mi * 16 + lr;
      int b = n >> 10, nn = n & 1023;
#pragma unroll
      for (int ni = 0; ni < 4; ++ni) {
        int fs = colBase - tsec * 768 + ni * 16 + lg * 4;
        int h = fs >> 6, d = fs & 63;           // d multiple of 4 -> 8B aligned
        size_t rowq = ((size_t)(b * 12 + h) * 1024 + nn) * 128;
        float v0 = acc[mi][ni][0] + bv4[ni].x;
        float v1 = acc[mi][ni][1] + bv4[ni].y;
        float v2 = acc[mi][ni][2] + bv4[ni].z;
        float v3 = acc[mi][ni][3] + bv4[ni].w;
        uint2 wq_, wk_;
        wq_.x = (uint32_t)f2bf(v0 * sc1) | ((uint32_t)f2bf(v1 * sc1) << 16);
        wq_.y = (uint32_t)f2bf(v2 * sc1) | ((uint32_t)f2bf(v3 * sc1) << 16);
        wk_.x = (uint32_t)f2bf(v0 * sc2) | ((uint32_t)f2bf(v1 * sc2) << 16);
        wk_.y = (uint32_t)f2bf(v2 * sc2) | ((uint32_t)f2bf(v3 * sc2) << 16);
        if (tsec == 0) {
          *(uint2*)(Qh + rowq + d)      = wq_;   // sc1 * q
          *(uint2*)(Kh + rowq + 64 + d) = wk_;   // sc2 * q
        } else {
          *(uint2*)(Kh + rowq + d)      = wq_;   // sc1 * k
          *(uint2*)(Qh + rowq + 64 + d) = wk_;   // sc2 * k
        }
      }
    }
  } else {
    // ---- normal orientation: lane holds 4 consecutive tokens at one feat -> Vt[d][n] packed ----
    gemm_core<false>(Aq, Bw, As, Bs, by * 128, bx * 128, acc);

    float bv[4];
#pragma unroll
    for (int ni = 0; ni < 4; ++ni) bv[ni] = bias[colBase + ni * 16 + lr];

#pragma unroll
    for (int mi = 0; mi < 4; ++mi) {
      int tok0 = by * 128 + wr * 64 + mi * 16 + lg * 4;
      int b = tok0 >> 10, n0 = tok0 & 1023;
#pragma unroll
      for (int ni = 0; ni < 4; ++ni) {
        int fs = colBase - 2 * 768 + ni * 16 + lr;
        int h = fs >> 6, d = fs & 63;
        float v0 = acc[mi][ni][0] + bv[ni];
        float v1 = acc[mi][ni][1] + bv[ni];
        float v2 = acc[mi][ni][2] + bv[ni];
        float v3 = acc[mi][ni][3] + bv[ni];
        uint2 w;
        w.x = (uint32_t)f2bf(v0) | ((uint32_t)f2bf(v1) << 16);
        w.y = (uint32_t)f2bf(v2) | ((uint32_t)f2bf(v3) << 16);
        *(uint2*)(Vt + ((size_t)((b * 12 + h) * 64 + d)) * 1024 + n0) = w;
      }
    }
  }
}

// ---------------- fused flash attention: KVBLK=64, 16 iterations, 3 blocks/CU (R17-proven) ----------------
// Denominator on the MFMA pipe: acc_sum = mfma(ones, pa) per ks-half (consistency with numerator free).
// S^T = Khat . Qhat^T (C1 pre-folded) ; p = exp2(C2*rcp(exp2(acc)+1)) ; O^T = V^T.P ; O /= sum
__global__ __launch_bounds__(256, 3) void k_attn(
    const u16* __restrict__ Qh, const u16* __restrict__ Kh, const u16* __restrict__ Vt,
    u16* __restrict__ attn) {
  __shared__ u16 Ks[64 * 128];        // K-tile [64 tok][128 feat], 16B-chunk XOR swizzle (row&7)
  __shared__ u16 Vs[2][64 * 64];      // Vt-tiles [64 d][64 tok], chunk swizzle (d&7)
  __shared__ u16 Ps[4][2][32 * 40];   // per-wave, per-ks-half P [32 i][32 j], stride 40 u16

  int bid = blockIdx.x;
  int wg = (bid & 7) * 96 + (bid >> 3);   // 768 = 8*96; a head's q-blocks stay on one XCD
  int bh = wg >> 3, qb = wg & 7;          // 8 q-blocks of 128 rows
  int b = bh / 12, h = bh % 12;

  const int t = threadIdx.x, lane = t & 63, wv = t >> 6;
  const int lr = lane & 15, lg = lane >> 4;

  const size_t khb = (size_t)bh * 1024 * 128;
  const size_t vtb = (size_t)bh * 64 * 1024;

  // Q fragments: qf[it][kk] = Qhat[token = qb*128 + wv*32 + it*16 + lr][k = kk*32 + lg*8 ..+8]
  bf16x8 qf[2][4];
  {
    const u16* qp = Qh + ((size_t)bh * 1024 + qb * 128 + wv * 32 + lr) * 128 + lg * 8;
#pragma unroll
    for (int it = 0; it < 2; ++it)
#pragma unroll
      for (int kk = 0; kk < 4; ++kk)
        qf[it][kk] = *(const bf16x8*)(qp + it * 16 * 128 + kk * 32);
  }

  // constant A-operand of bf16 1.0 for the denominator MFMA (no LDS, no loads)
  const short ONE = (short)0x3F80;
  const bf16x8 ones8 = {ONE, ONE, ONE, ONE, ONE, ONE, ONE, ONE};

#define STAGE_K(KT)                                                                            \
  {                                                                                            \
    _Pragma("unroll")                                                                          \
    for (int p = 0; p < 4; ++p) {                                                              \
      int idx = p * 256 + t;                                                                   \
      int row = idx >> 4;                                                                      \
      int cc  = (idx & 15) ^ (row & 7);                                                        \
      __builtin_amdgcn_global_load_lds(GLB_AS(Kh + khb + (size_t)((KT) * 64 + row) * 128 + cc * 8), \
                                       LDS_AS(Ks + idx * 8), 16, 0, 0);                        \
    }                                                                                          \
  }
#define STAGE_V(KT, BUF)                                                                       \
  {                                                                                            \
    _Pragma("unroll")                                                                          \
    for (int p = 0; p < 2; ++p) {                                                              \
      int idx = p * 256 + t;                                                                   \
      int d   = idx >> 3;                                                                      \
      int g   = (idx & 7) ^ (d & 7);                                                           \
      __builtin_amdgcn_global_load_lds(GLB_AS(Vt + vtb + (size_t)d * 1024 + (KT) * 64 + g * 8),\
                                       LDS_AS(Vs[BUF] + idx * 8), 16, 0, 0);                   \
    }                                                                                          \
  }

  STAGE_V(0, 0);
  STAGE_K(0);

  f32x4 acc_o[4][2];
#pragma unroll
  for (int dt = 0; dt < 4; ++dt)
#pragma unroll
    for (int it = 0; it < 2; ++it) acc_o[dt][it] = (f32x4){0.f, 0.f, 0.f, 0.f};
  f32x4 acc_sum[2];
#pragma unroll
  for (int it = 0; it < 2; ++it) acc_sum[it] = (f32x4){0.f, 0.f, 0.f, 0.f};

  const float C2 = -14.4269504089f;   // -10 * log2(e)

#pragma unroll 1
  for (int kt = 0; kt < 16; ++kt) {
    const int cur = kt & 1;
    __syncthreads();   // drains vmcnt(0): K(kt) and V(kt) landed; Vs[cur^1] free (PV(kt-1) done)

    if (kt < 15) STAGE_V(kt + 1, cur ^ 1);   // lands during QK^T below

    // ---- S^T tile: accs[jt][it]; rows j = jt*16+lg*4+r, cols i = it*16+lr ----
    f32x4 accs[4][2];
#pragma unroll
    for (int jt = 0; jt < 4; ++jt)
#pragma unroll
      for (int it = 0; it < 2; ++it) accs[jt][it] = (f32x4){0.f, 0.f, 0.f, 0.f};
    __builtin_amdgcn_s_setprio(1);
#pragma unroll
    for (int jt = 0; jt < 4; ++jt) {
#pragma unroll
      for (int kk = 0; kk < 4; ++kk) {
        int row = jt * 16 + lr;
        int cc  = (kk * 4 + lg) ^ (row & 7);
        bf16x8 kf = *(const bf16x8*)(Ks + row * 128 + cc * 8);
#pragma unroll
        for (int it = 0; it < 2; ++it)
          accs[jt][it] = __builtin_amdgcn_mfma_f32_16x16x32_bf16(kf, qf[it][kk], accs[jt][it], 0, 0, 0);
      }
    }
    __builtin_amdgcn_s_setprio(0);

    __syncthreads();   // all waves done reading Ks -> safe to overwrite (drain also lands V(kt+1))
    if (kt < 15) STAGE_K(kt + 1);   // lands during softmax+PV below

    // ---- p = exp2(C2 * rcp(exp2(acc)+1)); truncate to bf16 (pack_hi16) ----
#pragma unroll
    for (int jt = 0; jt < 4; ++jt) {
      const int ks = jt >> 1, jtl = jt & 1;
#pragma unroll
      for (int it = 0; it < 2; ++it) {
        float p0 = exp2_fast(C2 * __builtin_amdgcn_rcpf(exp2_fast(accs[jt][it][0]) + 1.0f));
        float p1 = exp2_fast(C2 * __builtin_amdgcn_rcpf(exp2_fast(accs[jt][it][1]) + 1.0f));
        float p2 = exp2_fast(C2 * __builtin_amdgcn_rcpf(exp2_fast(accs[jt][it][2]) + 1.0f));
        float p3 = exp2_fast(C2 * __builtin_amdgcn_rcpf(exp2_fast(accs[jt][it][3]) + 1.0f));
        uint2 w;
        w.x = pack_hi16(f2bits(p0), f2bits(p1));
        w.y = pack_hi16(f2bits(p2), f2bits(p3));
        *(uint2*)(&Ps[wv][ks][(it * 16 + lr) * 40 + jtl * 16 + lg * 4]) = w;
      }
    }

    // forbid compiler from reordering the P reads above the P writes
    asm volatile("" ::: "memory");

    // ---- O^T += mfma(V-frag, P-frag); denominator += mfma(ones, P-frag) ----
    {
      const u16* V0 = Vs[cur];
#pragma unroll
      for (int ks = 0; ks < 2; ++ks) {
        bf16x8 pa[2];
#pragma unroll
        for (int it = 0; it < 2; ++it)
          pa[it] = *(const bf16x8*)(&Ps[wv][ks][(it * 16 + lr) * 40 + lg * 8]);
        __builtin_amdgcn_s_setprio(1);
#pragma unroll
        for (int dt = 0; dt < 4; ++dt) {
          int row  = dt * 16 + lr;
          int slot = (ks * 4 + lg) ^ (lr & 7);
          bf16x8 vf = *(const bf16x8*)(V0 + row * 64 + slot * 8);
#pragma unroll
          for (int it = 0; it < 2; ++it)
            acc_o[dt][it] = __builtin_amdgcn_mfma_f32_16x16x32_bf16(vf, pa[it], acc_o[dt][it], 0, 0, 0);
        }
#pragma unroll
        for (int it = 0; it < 2; ++it)
          acc_sum[it] = __builtin_amdgcn_mfma_f32_16x16x32_bf16(ones8, pa[it], acc_sum[it], 0, 0, 0);
        __builtin_amdgcn_s_setprio(0);
      }
    }
  }
#undef STAGE_K
#undef STAGE_V

  // ---- denominator: every lane already holds its token's sum (col = lr); invert ----
  float rinv[2];
#pragma unroll
  for (int it = 0; it < 2; ++it)
    rinv[it] = __builtin_amdgcn_rcpf(acc_sum[it][0]);

  // ---- write O: token n = qb*128+wv*32+it*16+lr ; feature = h*64 + dt*16 + lg*4 + r ----
#pragma unroll
  for (int dt = 0; dt < 4; ++dt) {
#pragma unroll
    for (int it = 0; it < 2; ++it) {
      float v0 = acc_o[dt][it][0] * rinv[it];
      float v1 = acc_o[dt][it][1] * rinv[it];
      float v2 = acc_o[dt][it][2] * rinv[it];
      float v3 = acc_o[dt][it][3] * rinv[it];
      uint2 w;
      w.x = (uint32_t)f2bf(v0) | ((uint32_t)f2bf(v1) << 16);
      w.y = (uint32_t)f2bf(v2) | ((uint32_t)f2bf(v3) << 16);
      int n = qb * 128 + wv * 32 + it * 16 + lr;
      *(uint2*)(attn + ((size_t)(b * 1024 + n)) * 768 + h * 64 + dt * 16 + lg * 4) = w;
    }
  }
}

// ---------------- GEMM2: output projection (fp32 out, coalesced scalar stores) ----------------
__global__ __launch_bounds__(256) void k_gemm_proj(
    const u16* __restrict__ Ain, const u16* __restrict__ Bw, const float* __restrict__ bias,
    float* __restrict__ out) {
  __shared__ u16 As[3 * 128 * 32];
  __shared__ u16 Bs[3 * 128 * 32];
  int bid = blockIdx.x;
  int wg  = (bid & 7) * 48 + (bid >> 3);
  int bx  = wg % 6, by = wg / 6;

  f32x4 acc[4][4];
#pragma unroll
  for (int mi = 0; mi < 4; ++mi)
#pragma unroll
    for (int ni = 0; ni < 4; ++ni) acc[mi][ni] = (f32x4){0.f, 0.f, 0.f, 0.f};

  gemm_core<false>(Ain, Bw, As, Bs, by * 128, bx * 128, acc);

  const int t = threadIdx.x, lane = t & 63, wv = t >> 6;
  const int wr = wv >> 1, wc = wv & 1, lr = lane & 15, lg = lane >> 4;
  const int col0 = bx * 128 + wc * 64;

  float bv[4];
#pragma unroll
  for (int ni = 0; ni < 4; ++ni) bv[ni] = bias[col0 + ni * 16 + lr];

#pragma unroll
  for (int mi = 0; mi < 4; ++mi) {
    int tok0 = by * 128 + wr * 64 + mi * 16 + lg * 4;
#pragma unroll
    for (int ni = 0; ni < 4; ++ni) {
      int col = col0 + ni * 16 + lr;
#pragma unroll
      for (int r = 0; r < 4; ++r) {
        out[(size_t)(tok0 + r) * 768 + col] = acc[mi][ni][r] + bv[ni];
      }
    }
  }
}

// ---------------- launch ----------------
extern "C" void kernel_launch(void* const* d_in, const int* in_sizes, int n_in,
                              void* d_out, int out_size, void* d_ws, size_t ws_size,
                              hipStream_t stream) {
  (void)in_sizes; (void)n_in; (void)out_size;
  const float* x      = (const float*)d_in[0];
  const float* qkv_w  = (const float*)d_in[1];
  const float* qkv_b  = (const float*)d_in[2];
  const float* proj_w = (const float*)d_in[3];
  const float* proj_b = (const float*)d_in[4];
  float* out = (float*)d_out;

  uint8_t* ws = (uint8_t*)d_ws;
  u16* xb  = (u16*)(ws + 0);          // 8192*768  bf16 (reused as attn_out)
  u16* wqb = (u16*)(ws + 12582912);
  u16* wpb = (u16*)(ws + 16121856);
  u16* Qh  = (u16*)(ws + 17301504);
  u16* Kh  = (u16*)(ws + 42467328);
  u16* Vt  = (u16*)(ws + 80216064);   // [bh][d][n] written directly by k_gemm_qkv
  if (ws_size < 92798976) return;

  u16* attnb = xb;

  k_convert<<<2048, 256, 0, stream>>>(x, qkv_w, proj_w, xb, wqb, wpb);
  k_gemm_qkv<<<1152, 256, 0, stream>>>(xb, wqb, qkv_b, Qh, Kh, Vt);
  k_attn<<<768, 256, 0, stream>>>(Qh, Kh, Vt, attnb);
  k_gemm_proj<<<384, 256, 0, stream>>>(attnb, wpb, proj_b, out);
}

// Round 19
// 140.972 us; speedup vs baseline: 1.0805x; 1.0805x over previous
//
#include <hip/hip_runtime.h>
#include <hip/hip_bf16.h>
#include <stdint.h>

typedef unsigned short u16;
typedef __attribute__((ext_vector_type(8))) short bf16x8;
typedef __attribute__((ext_vector_type(4))) float f32x4;

#define LDS_AS(p) ((__attribute__((address_space(3))) void*)(p))
#define GLB_AS(p) ((__attribute__((address_space(1))) void*)(p))

__device__ __forceinline__ u16 f2bf(float f) {
  union { float f; uint32_t u; } v; v.f = f;
  uint32_t u = v.u;
  u += 0x7fffu + ((u >> 16) & 1u);
  return (u16)(u >> 16);
}

__device__ __forceinline__ float exp2_fast(float x) {  // 2^x via v_exp_f32
  float r;
  asm("v_exp_f32 %0, %1" : "=v"(r) : "v"(x));
  return r;
}

__device__ __forceinline__ uint32_t f2bits(float f) {
  union { float f; uint32_t u; } v; v.f = f; return v.u;
}
// dst = (hi16 of hi_src) << 16 | (hi16 of lo_src)  -- one v_perm_b32
__device__ __forceinline__ uint32_t pack_hi16(uint32_t lo_src, uint32_t hi_src) {
  return __builtin_amdgcn_perm(hi_src, lo_src, 0x07060302u);
}

// ---------------- fp32 -> bf16 conversion ----------------
__device__ __forceinline__ void cvt8(const float* __restrict__ s, u16* __restrict__ d) {
  const float4* sv = (const float4*)s;
  float4 a = sv[0], b = sv[1];
  uint4 o;
  o.x = (uint32_t)f2bf(a.x) | ((uint32_t)f2bf(a.y) << 16);
  o.y = (uint32_t)f2bf(a.z) | ((uint32_t)f2bf(a.w) << 16);
  o.z = (uint32_t)f2bf(b.x) | ((uint32_t)f2bf(b.y) << 16);
  o.w = (uint32_t)f2bf(b.z) | ((uint32_t)f2bf(b.w) << 16);
  *(uint4*)d = o;
}

__global__ __launch_bounds__(256) void k_convert(
    const float* __restrict__ x, const float* __restrict__ wq, const float* __restrict__ wp,
    u16* __restrict__ xb, u16* __restrict__ wqb, u16* __restrict__ wpb) {
  int tid = blockIdx.x * 256 + threadIdx.x;
  int np  = gridDim.x * 256;
  for (int i = tid; i < (8192*768)/8; i += np) cvt8(x  + (size_t)i*8, xb  + (size_t)i*8);
  for (int i = tid; i < (2304*768)/8; i += np) cvt8(wq + (size_t)i*8, wqb + (size_t)i*8);
  for (int i = tid; i < (768*768)/8;  i += np) cvt8(wp + (size_t)i*8, wpb + (size_t)i*8);
}

// ---------------- shared 128x128 bf16 GEMM mainloop, PIPELINED double-buffer ----------------
// One __syncthreads() per K-step: stage(kt+1) issued after it, compute(kt) from other buffer.
// SWAP=false: acc rows = A-rows (tokens), cols = B-rows (feats); SWAP=true: transposed.
template<bool SWAP>
__device__ __forceinline__ void gemm_core(const u16* __restrict__ A,
                                          const u16* __restrict__ B,
                                          u16* As, u16* Bs,   // each [2][128*32]
                                          int rowA0, int rowB0,
                                          f32x4 acc[4][4]) {
  const int t  = threadIdx.x;
  const int lane = t & 63;
  const int wv = t >> 6;
  const int wr = wv >> 1, wc = wv & 1;
  const int lr = lane & 15, lg = lane >> 4;

#define GSTAGE(KT, BUF)                                                                         \
  {                                                                                             \
    _Pragma("unroll")                                                                           \
    for (int p = 0; p < 2; ++p) {                                                               \
      int idx = p * 256 + t;                                                                    \
      int row = idx >> 2;                                                                       \
      int cc  = (idx & 3) ^ ((row >> 1) & 3);                                                   \
      __builtin_amdgcn_global_load_lds(GLB_AS(A + (size_t)(rowA0 + row) * 768 + (KT) * 32 + cc * 8), \
                                       LDS_AS(As + (BUF) * 4096 + idx * 8), 16, 0, 0);          \
    }                                                                                           \
    _Pragma("unroll")                                                                           \
    for (int p = 0; p < 2; ++p) {                                                               \
      int idx = p * 256 + t;                                                                    \
      int row = idx >> 2;                                                                       \
      int cc  = (idx & 3) ^ ((row >> 1) & 3);                                                   \
      __builtin_amdgcn_global_load_lds(GLB_AS(B + (size_t)(rowB0 + row) * 768 + (KT) * 32 + cc * 8), \
                                       LDS_AS(Bs + (BUF) * 4096 + idx * 8), 16, 0, 0);          \
    }                                                                                           \
  }

  GSTAGE(0, 0);   // prologue

#pragma unroll 1
  for (int kt = 0; kt < 24; ++kt) {
    const int cur = kt & 1;
    __syncthreads();   // drains vmcnt(0): stage(kt) landed; buf[cur^1] free to overwrite

    if (kt < 23) GSTAGE(kt + 1, cur ^ 1);   // lands during compute below

    const u16* Ab = As + cur * 4096;
    const u16* Bb = Bs + cur * 4096;
    bf16x8 af[4], bf_[4];
#pragma unroll
    for (int mi = 0; mi < 4; ++mi) {
      int row = wr * 64 + mi * 16 + lr;
      int cc  = lg ^ ((row >> 1) & 3);
      af[mi] = *(const bf16x8*)(Ab + row * 32 + cc * 8);
    }
#pragma unroll
    for (int ni = 0; ni < 4; ++ni) {
      int row = wc * 64 + ni * 16 + lr;
      int cc  = lg ^ ((row >> 1) & 3);
      bf_[ni] = *(const bf16x8*)(Bb + row * 32 + cc * 8);
    }
#pragma unroll
    for (int mi = 0; mi < 4; ++mi)
#pragma unroll
      for (int ni = 0; ni < 4; ++ni) {
        if (SWAP)
          acc[mi][ni] = __builtin_amdgcn_mfma_f32_16x16x32_bf16(bf_[ni], af[mi], acc[mi][ni], 0, 0, 0);
        else
          acc[mi][ni] = __builtin_amdgcn_mfma_f32_16x16x32_bf16(af[mi], bf_[ni], acc[mi][ni], 0, 0, 0);
      }
  }
#undef GSTAGE
}

// ---------------- GEMM1: qkv projection + scatter into Qhat/Khat/Vt, all-packed stores ----------------
// C1 = 0.4*log2(e) folded into sc1/sc2 so attn's softmax uses exp2(acc) directly.
__global__ __launch_bounds__(256) void k_gemm_qkv(
    const u16* __restrict__ Aq, const u16* __restrict__ Bw, const float* __restrict__ bias,
    u16* __restrict__ Qh, u16* __restrict__ Kh, u16* __restrict__ Vt) {
  __shared__ u16 As[2 * 128 * 32];
  __shared__ u16 Bs[2 * 128 * 32];
  int bid = blockIdx.x;
  int wg  = (bid & 7) * 144 + (bid >> 3);
  int bx  = wg % 18, by = wg / 18;

  const int t = threadIdx.x, lane = t & 63, wv = t >> 6;
  const int wr = wv >> 1, wc = wv & 1, lr = lane & 15, lg = lane >> 4;
  const int tsec = bx / 6;            // 0=q, 1=k, 2=v (uniform per block)
  const int colBase = bx * 128 + wc * 64;

  const float gam = 0.7905694150420949f;
  const float rC1 = __builtin_sqrtf(0.57707801636f);    // sqrt(0.4*log2e)
  const float sc1 = __builtin_sqrtf(0.09375f / gam) * rC1;
  const float sc2 = __builtin_sqrtf(0.03125f / gam) * rC1;

  f32x4 acc[4][4];
#pragma unroll
  for (int mi = 0; mi < 4; ++mi)
#pragma unroll
    for (int ni = 0; ni < 4; ++ni) acc[mi][ni] = (f32x4){0.f, 0.f, 0.f, 0.f};

  if (tsec < 2) {
    // ---- swapped orientation: lane holds 4 consecutive feats at one token ----
    gemm_core<true>(Aq, Bw, As, Bs, by * 128, bx * 128, acc);

    float4 bv4[4];
#pragma unroll
    for (int ni = 0; ni < 4; ++ni)
      bv4[ni] = *(const float4*)(bias + colBase + ni * 16 + lg * 4);

#pragma unroll
    for (int mi = 0; mi < 4; ++mi) {
      int n = by * 128 + wr * 64 + mi * 16 + lr;
      int b = n >> 10, nn = n & 1023;
#pragma unroll
      for (int ni = 0; ni < 4; ++ni) {
        int fs = colBase - tsec * 768 + ni * 16 + lg * 4;
        int h = fs >> 6, d = fs & 63;           // d multiple of 4 -> 8B aligned
        size_t rowq = ((size_t)(b * 12 + h) * 1024 + nn) * 128;
        float v0 = acc[mi][ni][0] + bv4[ni].x;
        float v1 = acc[mi][ni][1] + bv4[ni].y;
        float v2 = acc[mi][ni][2] + bv4[ni].z;
        float v3 = acc[mi][ni][3] + bv4[ni].w;
        uint2 wq_, wk_;
        wq_.x = (uint32_t)f2bf(v0 * sc1) | ((uint32_t)f2bf(v1 * sc1) << 16);
        wq_.y = (uint32_t)f2bf(v2 * sc1) | ((uint32_t)f2bf(v3 * sc1) << 16);
        wk_.x = (uint32_t)f2bf(v0 * sc2) | ((uint32_t)f2bf(v1 * sc2) << 16);
        wk_.y = (uint32_t)f2bf(v2 * sc2) | ((uint32_t)f2bf(v3 * sc2) << 16);
        if (tsec == 0) {
          *(uint2*)(Qh + rowq + d)      = wq_;   // sc1 * q
          *(uint2*)(Kh + rowq + 64 + d) = wk_;   // sc2 * q
        } else {
          *(uint2*)(Kh + rowq + d)      = wq_;   // sc1 * k
          *(uint2*)(Qh + rowq + 64 + d) = wk_;   // sc2 * k
        }
      }
    }
  } else {
    // ---- normal orientation: lane holds 4 consecutive tokens at one feat -> Vt[d][n] packed ----
    gemm_core<false>(Aq, Bw, As, Bs, by * 128, bx * 128, acc);

    float bv[4];
#pragma unroll
    for (int ni = 0; ni < 4; ++ni) bv[ni] = bias[colBase + ni * 16 + lr];

#pragma unroll
    for (int mi = 0; mi < 4; ++mi) {
      int tok0 = by * 128 + wr * 64 + mi * 16 + lg * 4;
      int b = tok0 >> 10, n0 = tok0 & 1023;
#pragma unroll
      for (int ni = 0; ni < 4; ++ni) {
        int fs = colBase - 2 * 768 + ni * 16 + lr;
        int h = fs >> 6, d = fs & 63;
        float v0 = acc[mi][ni][0] + bv[ni];
        float v1 = acc[mi][ni][1] + bv[ni];
        float v2 = acc[mi][ni][2] + bv[ni];
        float v3 = acc[mi][ni][3] + bv[ni];
        uint2 w;
        w.x = (uint32_t)f2bf(v0) | ((uint32_t)f2bf(v1) << 16);
        w.y = (uint32_t)f2bf(v2) | ((uint32_t)f2bf(v3) << 16);
        *(uint2*)(Vt + ((size_t)((b * 12 + h) * 64 + d)) * 1024 + n0) = w;
      }
    }
  }
}

// ---------------- fused flash attention: KVBLK=64, 16 iterations, 3 blocks/CU ----------------
// R14 structure; denominator on the MFMA pipe: acc_sum = mfma(ones, pa) per ks-half.
// The sum is computed from the SAME truncated-bf16 P the numerator uses -> consistency free.
// S^T = Khat . Qhat^T (C1 pre-folded) ; p = exp2(C2*rcp(exp2(acc)+1)) ; O^T = V^T.P ; O /= sum
__global__ __launch_bounds__(256, 3) void k_attn(
    const u16* __restrict__ Qh, const u16* __restrict__ Kh, const u16* __restrict__ Vt,
    u16* __restrict__ attn) {
  __shared__ u16 Ks[64 * 128];        // K-tile [64 tok][128 feat], 16B-chunk XOR swizzle (row&7)
  __shared__ u16 Vs[2][64 * 64];      // Vt-tiles [64 d][64 tok], chunk swizzle (d&7)
  __shared__ u16 Ps[4][2][32 * 40];   // per-wave, per-ks-half P [32 i][32 j], stride 40 u16

  int bid = blockIdx.x;
  int wg = (bid & 7) * 96 + (bid >> 3);   // 768 = 8*96; a head's q-blocks stay on one XCD
  int bh = wg >> 3, qb = wg & 7;          // 8 q-blocks of 128 rows
  int b = bh / 12, h = bh % 12;

  const int t = threadIdx.x, lane = t & 63, wv = t >> 6;
  const int lr = lane & 15, lg = lane >> 4;

  const size_t khb = (size_t)bh * 1024 * 128;
  const size_t vtb = (size_t)bh * 64 * 1024;

  // Q fragments: qf[it][kk] = Qhat[token = qb*128 + wv*32 + it*16 + lr][k = kk*32 + lg*8 ..+8]
  bf16x8 qf[2][4];
  {
    const u16* qp = Qh + ((size_t)bh * 1024 + qb * 128 + wv * 32 + lr) * 128 + lg * 8;
#pragma unroll
    for (int it = 0; it < 2; ++it)
#pragma unroll
      for (int kk = 0; kk < 4; ++kk)
        qf[it][kk] = *(const bf16x8*)(qp + it * 16 * 128 + kk * 32);
  }

  // constant A-operand of bf16 1.0 for the denominator MFMA (no LDS, no loads)
  const short ONE = (short)0x3F80;
  const bf16x8 ones8 = {ONE, ONE, ONE, ONE, ONE, ONE, ONE, ONE};

#define STAGE_K(KT)                                                                            \
  {                                                                                            \
    _Pragma("unroll")                                                                          \
    for (int p = 0; p < 4; ++p) {                                                              \
      int idx = p * 256 + t;                                                                   \
      int row = idx >> 4;                                                                      \
      int cc  = (idx & 15) ^ (row & 7);                                                        \
      __builtin_amdgcn_global_load_lds(GLB_AS(Kh + khb + (size_t)((KT) * 64 + row) * 128 + cc * 8), \
                                       LDS_AS(Ks + idx * 8), 16, 0, 0);                        \
    }                                                                                          \
  }
#define STAGE_V(KT, BUF)                                                                       \
  {                                                                                            \
    _Pragma("unroll")                                                                          \
    for (int p = 0; p < 2; ++p) {                                                              \
      int idx = p * 256 + t;                                                                   \
      int d   = idx >> 3;                                                                      \
      int g   = (idx & 7) ^ (d & 7);                                                           \
      __builtin_amdgcn_global_load_lds(GLB_AS(Vt + vtb + (size_t)d * 1024 + (KT) * 64 + g * 8),\
                                       LDS_AS(Vs[BUF] + idx * 8), 16, 0, 0);                   \
    }                                                                                          \
  }

  STAGE_V(0, 0);
  STAGE_K(0);

  f32x4 acc_o[4][2];
#pragma unroll
  for (int dt = 0; dt < 4; ++dt)
#pragma unroll
    for (int it = 0; it < 2; ++it) acc_o[dt][it] = (f32x4){0.f, 0.f, 0.f, 0.f};
  f32x4 acc_sum[2];
#pragma unroll
  for (int it = 0; it < 2; ++it) acc_sum[it] = (f32x4){0.f, 0.f, 0.f, 0.f};

  const float C2 = -14.4269504089f;   // -10 * log2(e)

#pragma unroll 1
  for (int kt = 0; kt < 16; ++kt) {
    const int cur = kt & 1;
    __syncthreads();   // drains vmcnt(0): K(kt) and V(kt) landed; Vs[cur^1] free (PV(kt-1) done)

    if (kt < 15) STAGE_V(kt + 1, cur ^ 1);   // lands during QK^T below

    // ---- S^T tile: accs[jt][it]; rows j = jt*16+lg*4+r, cols i = it*16+lr ----
    f32x4 accs[4][2];
#pragma unroll
    for (int jt = 0; jt < 4; ++jt)
#pragma unroll
      for (int it = 0; it < 2; ++it) accs[jt][it] = (f32x4){0.f, 0.f, 0.f, 0.f};
    __builtin_amdgcn_s_setprio(1);
#pragma unroll
    for (int jt = 0; jt < 4; ++jt) {
#pragma unroll
      for (int kk = 0; kk < 4; ++kk) {
        int row = jt * 16 + lr;
        int cc  = (kk * 4 + lg) ^ (row & 7);
        bf16x8 kf = *(const bf16x8*)(Ks + row * 128 + cc * 8);
#pragma unroll
        for (int it = 0; it < 2; ++it)
          accs[jt][it] = __builtin_amdgcn_mfma_f32_16x16x32_bf16(kf, qf[it][kk], accs[jt][it], 0, 0, 0);
      }
    }
    __builtin_amdgcn_s_setprio(0);

    __syncthreads();   // all waves done reading Ks -> safe to overwrite (drain also lands V(kt+1))
    if (kt < 15) STAGE_K(kt + 1);   // lands during softmax+PV below

    // ---- p = exp2(C2 * rcp(exp2(acc)+1)); truncate to bf16 (pack_hi16) ----
#pragma unroll
    for (int jt = 0; jt < 4; ++jt) {
      const int ks = jt >> 1, jtl = jt & 1;
#pragma unroll
      for (int it = 0; it < 2; ++it) {
        float p0 = exp2_fast(C2 * __builtin_amdgcn_rcpf(exp2_fast(accs[jt][it][0]) + 1.0f));
        float p1 = exp2_fast(C2 * __builtin_amdgcn_rcpf(exp2_fast(accs[jt][it][1]) + 1.0f));
        float p2 = exp2_fast(C2 * __builtin_amdgcn_rcpf(exp2_fast(accs[jt][it][2]) + 1.0f));
        float p3 = exp2_fast(C2 * __builtin_amdgcn_rcpf(exp2_fast(accs[jt][it][3]) + 1.0f));
        uint2 w;
        w.x = pack_hi16(f2bits(p0), f2bits(p1));
        w.y = pack_hi16(f2bits(p2), f2bits(p3));
        *(uint2*)(&Ps[wv][ks][(it * 16 + lr) * 40 + jtl * 16 + lg * 4]) = w;
      }
    }

    // forbid compiler from reordering the P reads above the P writes
    asm volatile("" ::: "memory");

    // ---- O^T += mfma(V-frag, P-frag); denominator += mfma(ones, P-frag) ----
    {
      const u16* V0 = Vs[cur];
#pragma unroll
      for (int ks = 0; ks < 2; ++ks) {
        bf16x8 pa[2];
#pragma unroll
        for (int it = 0; it < 2; ++it)
          pa[it] = *(const bf16x8*)(&Ps[wv][ks][(it * 16 + lr) * 40 + lg * 8]);
        __builtin_amdgcn_s_setprio(1);
#pragma unroll
        for (int dt = 0; dt < 4; ++dt) {
          int row  = dt * 16 + lr;
          int slot = (ks * 4 + lg) ^ (lr & 7);
          bf16x8 vf = *(const bf16x8*)(V0 + row * 64 + slot * 8);
#pragma unroll
          for (int it = 0; it < 2; ++it)
            acc_o[dt][it] = __builtin_amdgcn_mfma_f32_16x16x32_bf16(vf, pa[it], acc_o[dt][it], 0, 0, 0);
        }
#pragma unroll
        for (int it = 0; it < 2; ++it)
          acc_sum[it] = __builtin_amdgcn_mfma_f32_16x16x32_bf16(ones8, pa[it], acc_sum[it], 0, 0, 0);
        __builtin_amdgcn_s_setprio(0);
      }
    }
  }
#undef STAGE_K
#undef STAGE_V

  // ---- denominator: every lane already holds its token's sum (col = lr); invert ----
  float rinv[2];
#pragma unroll
  for (int it = 0; it < 2; ++it)
    rinv[it] = __builtin_amdgcn_rcpf(acc_sum[it][0]);

  // ---- write O: token n = qb*128+wv*32+it*16+lr ; feature = h*64 + dt*16 + lg*4 + r ----
#pragma unroll
  for (int dt = 0; dt < 4; ++dt) {
#pragma unroll
    for (int it = 0; it < 2; ++it) {
      float v0 = acc_o[dt][it][0] * rinv[it];
      float v1 = acc_o[dt][it][1] * rinv[it];
      float v2 = acc_o[dt][it][2] * rinv[it];
      float v3 = acc_o[dt][it][3] * rinv[it];
      uint2 w;
      w.x = (uint32_t)f2bf(v0) | ((uint32_t)f2bf(v1) << 16);
      w.y = (uint32_t)f2bf(v2) | ((uint32_t)f2bf(v3) << 16);
      int n = qb * 128 + wv * 32 + it * 16 + lr;
      *(uint2*)(attn + ((size_t)(b * 1024 + n)) * 768 + h * 64 + dt * 16 + lg * 4) = w;
    }
  }
}

// ---------------- GEMM2: output projection (fp32 out, coalesced scalar stores) ----------------
__global__ __launch_bounds__(256) void k_gemm_proj(
    const u16* __restrict__ Ain, const u16* __restrict__ Bw, const float* __restrict__ bias,
    float* __restrict__ out) {
  __shared__ u16 As[2 * 128 * 32];
  __shared__ u16 Bs[2 * 128 * 32];
  int bid = blockIdx.x;
  int wg  = (bid & 7) * 48 + (bid >> 3);
  int bx  = wg % 6, by = wg / 6;

  f32x4 acc[4][4];
#pragma unroll
  for (int mi = 0; mi < 4; ++mi)
#pragma unroll
    for (int ni = 0; ni < 4; ++ni) acc[mi][ni] = (f32x4){0.f, 0.f, 0.f, 0.f};

  gemm_core<false>(Ain, Bw, As, Bs, by * 128, bx * 128, acc);

  const int t = threadIdx.x, lane = t & 63, wv = t >> 6;
  const int wr = wv >> 1, wc = wv & 1, lr = lane & 15, lg = lane >> 4;
  const int col0 = bx * 128 + wc * 64;

  float bv[4];
#pragma unroll
  for (int ni = 0; ni < 4; ++ni) bv[ni] = bias[col0 + ni * 16 + lr];

#pragma unroll
  for (int mi = 0; mi < 4; ++mi) {
    int tok0 = by * 128 + wr * 64 + mi * 16 + lg * 4;
#pragma unroll
    for (int ni = 0; ni < 4; ++ni) {
      int col = col0 + ni * 16 + lr;
#pragma unroll
      for (int r = 0; r < 4; ++r) {
        out[(size_t)(tok0 + r) * 768 + col] = acc[mi][ni][r] + bv[ni];
      }
    }
  }
}

// ---------------- launch ----------------
extern "C" void kernel_launch(void* const* d_in, const int* in_sizes, int n_in,
                              void* d_out, int out_size, void* d_ws, size_t ws_size,
                              hipStream_t stream) {
  (void)in_sizes; (void)n_in; (void)out_size;
  const float* x      = (const float*)d_in[0];
  const float* qkv_w  = (const float*)d_in[1];
  const float* qkv_b  = (const float*)d_in[2];
  const float* proj_w = (const float*)d_in[3];
  const float* proj_b = (const float*)d_in[4];
  float* out = (float*)d_out;

  uint8_t* ws = (uint8_t*)d_ws;
  u16* xb  = (u16*)(ws + 0);          // 8192*768  bf16 (reused as attn_out)
  u16* wqb = (u16*)(ws + 12582912);
  u16* wpb = (u16*)(ws + 16121856);
  u16* Qh  = (u16*)(ws + 17301504);
  u16* Kh  = (u16*)(ws + 42467328);
  u16* Vt  = (u16*)(ws + 80216064);   // [bh][d][n] written directly by k_gemm_qkv
  if (ws_size < 92798976) return;

  u16* attnb = xb;

  k_convert<<<2048, 256, 0, stream>>>(x, qkv_w, proj_w, xb, wqb, wpb);
  k_gemm_qkv<<<1152, 256, 0, stream>>>(xb, wqb, qkv_b, Qh, Kh, Vt);
  k_attn<<<768, 256, 0, stream>>>(Qh, Kh, Vt, attnb);
  k_gemm_proj<<<384, 256, 0, stream>>>(attnb, wpb, proj_b, out);
}

// Round 20
// 136.567 us; speedup vs baseline: 1.1154x; 1.0323x over previous
//
#include <hip/hip_runtime.h>
#include <hip/hip_bf16.h>
#include <stdint.h>

typedef unsigned short u16;
typedef __attribute__((ext_vector_type(8))) short bf16x8;
typedef __attribute__((ext_vector_type(4))) float f32x4;

#define LDS_AS(p) ((__attribute__((address_space(3))) void*)(p))
#define GLB_AS(p) ((__attribute__((address_space(1))) void*)(p))

__device__ __forceinline__ u16 f2bf(float f) {
  union { float f; uint32_t u; } v; v.f = f;
  uint32_t u = v.u;
  u += 0x7fffu + ((u >> 16) & 1u);
  return (u16)(u >> 16);
}

__device__ __forceinline__ float exp2_fast(float x) {  // 2^x via v_exp_f32
  float r;
  asm("v_exp_f32 %0, %1" : "=v"(r) : "v"(x));
  return r;
}

__device__ __forceinline__ float bits2f(uint32_t u) {
  union { uint32_t u; float f; } v; v.u = u; return v.f;
}
__device__ __forceinline__ uint32_t f2bits(float f) {
  union { float f; uint32_t u; } v; v.f = f; return v.u;
}
// dst = (hi16 of hi_src) << 16 | (hi16 of lo_src)  -- one v_perm_b32
__device__ __forceinline__ uint32_t pack_hi16(uint32_t lo_src, uint32_t hi_src) {
  return __builtin_amdgcn_perm(hi_src, lo_src, 0x07060302u);
}

// scale a packed bf16x8 by 1/3 (two bf16 per u32; truncation repack) -- one-time cost
__device__ __forceinline__ bf16x8 scale_third(bf16x8 v) {
  union { bf16x8 v; uint32_t u[4]; } a, r;
  a.v = v;
  const float K = 0.33333333333f;
#pragma unroll
  for (int i = 0; i < 4; ++i) {
    float lo = bits2f(a.u[i] << 16) * K;
    float hi = bits2f(a.u[i] & 0xFFFF0000u) * K;
    r.u[i] = pack_hi16(f2bits(lo), f2bits(hi));
  }
  return r.v;
}

// ---------------- fp32 -> bf16 conversion ----------------
__device__ __forceinline__ void cvt8(const float* __restrict__ s, u16* __restrict__ d) {
  const float4* sv = (const float4*)s;
  float4 a = sv[0], b = sv[1];
  uint4 o;
  o.x = (uint32_t)f2bf(a.x) | ((uint32_t)f2bf(a.y) << 16);
  o.y = (uint32_t)f2bf(a.z) | ((uint32_t)f2bf(a.w) << 16);
  o.z = (uint32_t)f2bf(b.x) | ((uint32_t)f2bf(b.y) << 16);
  o.w = (uint32_t)f2bf(b.z) | ((uint32_t)f2bf(b.w) << 16);
  *(uint4*)d = o;
}

__global__ __launch_bounds__(256) void k_convert(
    const float* __restrict__ x, const float* __restrict__ wq, const float* __restrict__ wp,
    u16* __restrict__ xb, u16* __restrict__ wqb, u16* __restrict__ wpb) {
  int tid = blockIdx.x * 256 + threadIdx.x;
  int np  = gridDim.x * 256;
  for (int i = tid; i < (8192*768)/8; i += np) cvt8(x  + (size_t)i*8, xb  + (size_t)i*8);
  for (int i = tid; i < (2304*768)/8; i += np) cvt8(wq + (size_t)i*8, wqb + (size_t)i*8);
  for (int i = tid; i < (768*768)/8;  i += np) cvt8(wp + (size_t)i*8, wpb + (size_t)i*8);
}

// ---------------- shared 128x128 bf16 GEMM mainloop, PIPELINED double-buffer ----------------
// One __syncthreads() per K-step: stage(kt+1) issued after it, compute(kt) from other buffer.
// SWAP=false: acc rows = A-rows (tokens), cols = B-rows (feats); SWAP=true: transposed.
template<bool SWAP>
__device__ __forceinline__ void gemm_core(const u16* __restrict__ A,
                                          const u16* __restrict__ B,
                                          u16* As, u16* Bs,   // each [2][128*32]
                                          int rowA0, int rowB0,
                                          f32x4 acc[4][4]) {
  const int t  = threadIdx.x;
  const int lane = t & 63;
  const int wv = t >> 6;
  const int wr = wv >> 1, wc = wv & 1;
  const int lr = lane & 15, lg = lane >> 4;

#define GSTAGE(KT, BUF)                                                                         \
  {                                                                                             \
    _Pragma("unroll")                                                                           \
    for (int p = 0; p < 2; ++p) {                                                               \
      int idx = p * 256 + t;                                                                    \
      int row = idx >> 2;                                                                       \
      int cc  = (idx & 3) ^ ((row >> 1) & 3);                                                   \
      __builtin_amdgcn_global_load_lds(GLB_AS(A + (size_t)(rowA0 + row) * 768 + (KT) * 32 + cc * 8), \
                                       LDS_AS(As + (BUF) * 4096 + idx * 8), 16, 0, 0);          \
    }                                                                                           \
    _Pragma("unroll")                                                                           \
    for (int p = 0; p < 2; ++p) {                                                               \
      int idx = p * 256 + t;                                                                    \
      int row = idx >> 2;                                                                       \
      int cc  = (idx & 3) ^ ((row >> 1) & 3);                                                   \
      __builtin_amdgcn_global_load_lds(GLB_AS(B + (size_t)(rowB0 + row) * 768 + (KT) * 32 + cc * 8), \
                                       LDS_AS(Bs + (BUF) * 4096 + idx * 8), 16, 0, 0);          \
    }                                                                                           \
  }

  GSTAGE(0, 0);   // prologue

#pragma unroll 1
  for (int kt = 0; kt < 24; ++kt) {
    const int cur = kt & 1;
    __syncthreads();   // drains vmcnt(0): stage(kt) landed; buf[cur^1] free to overwrite

    if (kt < 23) GSTAGE(kt + 1, cur ^ 1);   // lands during compute below

    const u16* Ab = As + cur * 4096;
    const u16* Bb = Bs + cur * 4096;
    bf16x8 af[4], bf_[4];
#pragma unroll
    for (int mi = 0; mi < 4; ++mi) {
      int row = wr * 64 + mi * 16 + lr;
      int cc  = lg ^ ((row >> 1) & 3);
      af[mi] = *(const bf16x8*)(Ab + row * 32 + cc * 8);
    }
#pragma unroll
    for (int ni = 0; ni < 4; ++ni) {
      int row = wc * 64 + ni * 16 + lr;
      int cc  = lg ^ ((row >> 1) & 3);
      bf_[ni] = *(const bf16x8*)(Bb + row * 32 + cc * 8);
    }
#pragma unroll
    for (int mi = 0; mi < 4; ++mi)
#pragma unroll
      for (int ni = 0; ni < 4; ++ni) {
        if (SWAP)
          acc[mi][ni] = __builtin_amdgcn_mfma_f32_16x16x32_bf16(bf_[ni], af[mi], acc[mi][ni], 0, 0, 0);
        else
          acc[mi][ni] = __builtin_amdgcn_mfma_f32_16x16x32_bf16(af[mi], bf_[ni], acc[mi][ni], 0, 0, 0);
      }
  }
#undef GSTAGE
}

// ---------------- GEMM1: qkv projection -> Qs*=sc1*q, Ks*=sc1*k (64-dim rows), Vt ----------------
// No duplication: attn reconstructs the c2 term via register-scaled K* (1/3 fold).
__global__ __launch_bounds__(256) void k_gemm_qkv(
    const u16* __restrict__ Aq, const u16* __restrict__ Bw, const float* __restrict__ bias,
    u16* __restrict__ Qh, u16* __restrict__ Kh, u16* __restrict__ Vt) {
  __shared__ u16 As[2 * 128 * 32];
  __shared__ u16 Bs[2 * 128 * 32];
  int bid = blockIdx.x;
  int wg  = (bid & 7) * 144 + (bid >> 3);
  int bx  = wg % 18, by = wg / 18;

  const int t = threadIdx.x, lane = t & 63, wv = t >> 6;
  const int wr = wv >> 1, wc = wv & 1, lr = lane & 15, lg = lane >> 4;
  const int tsec = bx / 6;            // 0=q, 1=k, 2=v (uniform per block)
  const int colBase = bx * 128 + wc * 64;

  const float gam = 0.7905694150420949f;
  const float rC1 = __builtin_sqrtf(0.57707801636f);    // sqrt(0.4*log2e)
  const float sc1 = __builtin_sqrtf(0.09375f / gam) * rC1;

  f32x4 acc[4][4];
#pragma unroll
  for (int mi = 0; mi < 4; ++mi)
#pragma unroll
    for (int ni = 0; ni < 4; ++ni) acc[mi][ni] = (f32x4){0.f, 0.f, 0.f, 0.f};

  if (tsec < 2) {
    // ---- swapped orientation: lane holds 4 consecutive feats at one token ----
    gemm_core<true>(Aq, Bw, As, Bs, by * 128, bx * 128, acc);

    u16* dst = (tsec == 0) ? Qh : Kh;

    float4 bv4[4];
#pragma unroll
    for (int ni = 0; ni < 4; ++ni)
      bv4[ni] = *(const float4*)(bias + colBase + ni * 16 + lg * 4);

#pragma unroll
    for (int mi = 0; mi < 4; ++mi) {
      int n = by * 128 + wr * 64 + mi * 16 + lr;
      int b = n >> 10, nn = n & 1023;
#pragma unroll
      for (int ni = 0; ni < 4; ++ni) {
        int fs = colBase - tsec * 768 + ni * 16 + lg * 4;
        int h = fs >> 6, d = fs & 63;           // d multiple of 4 -> 8B aligned
        size_t rowq = ((size_t)(b * 12 + h) * 1024 + nn) * 64;
        float v0 = (acc[mi][ni][0] + bv4[ni].x) * sc1;
        float v1 = (acc[mi][ni][1] + bv4[ni].y) * sc1;
        float v2 = (acc[mi][ni][2] + bv4[ni].z) * sc1;
        float v3 = (acc[mi][ni][3] + bv4[ni].w) * sc1;
        uint2 w;
        w.x = (uint32_t)f2bf(v0) | ((uint32_t)f2bf(v1) << 16);
        w.y = (uint32_t)f2bf(v2) | ((uint32_t)f2bf(v3) << 16);
        *(uint2*)(dst + rowq + d) = w;
      }
    }
  } else {
    // ---- normal orientation: lane holds 4 consecutive tokens at one feat -> Vt[d][n] packed ----
    gemm_core<false>(Aq, Bw, As, Bs, by * 128, bx * 128, acc);

    float bv[4];
#pragma unroll
    for (int ni = 0; ni < 4; ++ni) bv[ni] = bias[colBase + ni * 16 + lr];

#pragma unroll
    for (int mi = 0; mi < 4; ++mi) {
      int tok0 = by * 128 + wr * 64 + mi * 16 + lg * 4;
      int b = tok0 >> 10, n0 = tok0 & 1023;
#pragma unroll
      for (int ni = 0; ni < 4; ++ni) {
        int fs = colBase - 2 * 768 + ni * 16 + lr;
        int h = fs >> 6, d = fs & 63;
        float v0 = acc[mi][ni][0] + bv[ni];
        float v1 = acc[mi][ni][1] + bv[ni];
        float v2 = acc[mi][ni][2] + bv[ni];
        float v3 = acc[mi][ni][3] + bv[ni];
        uint2 w;
        w.x = (uint32_t)f2bf(v0) | ((uint32_t)f2bf(v1) << 16);
        w.y = (uint32_t)f2bf(v2) | ((uint32_t)f2bf(v3) << 16);
        *(uint2*)(Vt + ((size_t)((b * 12 + h) * 64 + d)) * 1024 + n0) = w;
      }
    }
  }
}

// ---------------- fused flash attention: two-term D=64 QK^T, KVBLK=64, 3 blocks/CU ----------------
// accs[j][i] = mfma(K*_j, Q*_i) + mfma(Q*_j, (1/3)K*_i)  ==  c1 q_i.k_j + c2 k_i.q_j (C1 folded)
// Denominator on the MFMA pipe: acc_sum = mfma(ones, pa) per ks-half.
// p = exp2(C2*rcp(exp2(acc)+1)) ; O^T = V^T.P ; O /= sum
__global__ __launch_bounds__(256, 3) void k_attn(
    const u16* __restrict__ Qh, const u16* __restrict__ Kh, const u16* __restrict__ Vt,
    u16* __restrict__ attn) {
  __shared__ u16 Ks[64 * 64];         // K*-tile [64 tok][64 feat], chunk swizzle (row&7)
  __shared__ u16 Qs[64 * 64];         // Q*-tile [64 tok][64 feat], chunk swizzle (row&7)
  __shared__ u16 Vs[2][64 * 64];      // Vt-tiles [64 d][64 tok], chunk swizzle (d&7)
  __shared__ u16 Ps[4][2][32 * 40];   // per-wave, per-ks-half P [32 i][32 j], stride 40 u16

  int bid = blockIdx.x;
  int wg = (bid & 7) * 96 + (bid >> 3);   // 768 = 8*96; a head's q-blocks stay on one XCD
  int bh = wg >> 3, qb = wg & 7;          // 8 q-blocks of 128 rows
  int b = bh / 12, h = bh % 12;

  const int t = threadIdx.x, lane = t & 63, wv = t >> 6;
  const int lr = lane & 15, lg = lane >> 4;

  const size_t khb = (size_t)bh * 1024 * 64;
  const size_t vtb = (size_t)bh * 64 * 1024;

  // Register fragments for own tokens i = qb*128 + wv*32 + it*16 + lr:
  // qf = Q*_i ; kreg = (1/3) * K*_i   (feats kk*32 + lg*8 .. +8)
  bf16x8 qf[2][2], kreg[2][2];
  {
    const u16* qp = Qh + ((size_t)bh * 1024 + qb * 128 + wv * 32 + lr) * 64 + lg * 8;
    const u16* kp = Kh + ((size_t)bh * 1024 + qb * 128 + wv * 32 + lr) * 64 + lg * 8;
#pragma unroll
    for (int it = 0; it < 2; ++it)
#pragma unroll
      for (int kk = 0; kk < 2; ++kk) {
        qf[it][kk]   = *(const bf16x8*)(qp + it * 16 * 64 + kk * 32);
        kreg[it][kk] = scale_third(*(const bf16x8*)(kp + it * 16 * 64 + kk * 32));
      }
  }

  // constant A-operand of bf16 1.0 for the denominator MFMA (no LDS, no loads)
  const short ONE = (short)0x3F80;
  const bf16x8 ones8 = {ONE, ONE, ONE, ONE, ONE, ONE, ONE, ONE};

// stage K*(KT) and Q*(KT): 2+2 loads (each tile 8KB: 512 chunks / 256 threads)
#define STAGE_KQ(KT)                                                                           \
  {                                                                                            \
    _Pragma("unroll")                                                                          \
    for (int p = 0; p < 2; ++p) {                                                              \
      int idx = p * 256 + t;                                                                   \
      int row = idx >> 3;                                                                      \
      int g   = (idx & 7) ^ (row & 7);                                                         \
      __builtin_amdgcn_global_load_lds(GLB_AS(Kh + khb + (size_t)((KT) * 64 + row) * 64 + g * 8), \
                                       LDS_AS(Ks + idx * 8), 16, 0, 0);                        \
    }                                                                                          \
    _Pragma("unroll")                                                                          \
    for (int p = 0; p < 2; ++p) {                                                              \
      int idx = p * 256 + t;                                                                   \
      int row = idx >> 3;                                                                      \
      int g   = (idx & 7) ^ (row & 7);                                                         \
      __builtin_amdgcn_global_load_lds(GLB_AS(Qh + khb + (size_t)((KT) * 64 + row) * 64 + g * 8), \
                                       LDS_AS(Qs + idx * 8), 16, 0, 0);                        \
    }                                                                                          \
  }
#define STAGE_V(KT, BUF)                                                                       \
  {                                                                                            \
    _Pragma("unroll")                                                                          \
    for (int p = 0; p < 2; ++p) {                                                              \
      int idx = p * 256 + t;                                                                   \
      int d   = idx >> 3;                                                                      \
      int g   = (idx & 7) ^ (d & 7);                                                           \
      __builtin_amdgcn_global_load_lds(GLB_AS(Vt + vtb + (size_t)d * 1024 + (KT) * 64 + g * 8),\
                                       LDS_AS(Vs[BUF] + idx * 8), 16, 0, 0);                   \
    }                                                                                          \
  }

  STAGE_V(0, 0);
  STAGE_KQ(0);

  f32x4 acc_o[4][2];
#pragma unroll
  for (int dt = 0; dt < 4; ++dt)
#pragma unroll
    for (int it = 0; it < 2; ++it) acc_o[dt][it] = (f32x4){0.f, 0.f, 0.f, 0.f};
  f32x4 acc_sum[2];
#pragma unroll
  for (int it = 0; it < 2; ++it) acc_sum[it] = (f32x4){0.f, 0.f, 0.f, 0.f};

  const float C2 = -14.4269504089f;   // -10 * log2(e)

#pragma unroll 1
  for (int kt = 0; kt < 16; ++kt) {
    const int cur = kt & 1;
    __syncthreads();   // drains vmcnt(0): K*/Q*(kt) and V(kt) landed; Vs[cur^1] free

    if (kt < 15) STAGE_V(kt + 1, cur ^ 1);   // lands during QK^T below

    // ---- S^T tile: accs[jt][it]; rows j = jt*16+lg*4+r, cols i = it*16+lr ----
    f32x4 accs[4][2];
#pragma unroll
    for (int jt = 0; jt < 4; ++jt)
#pragma unroll
      for (int it = 0; it < 2; ++it) accs[jt][it] = (f32x4){0.f, 0.f, 0.f, 0.f};
    __builtin_amdgcn_s_setprio(1);
#pragma unroll
    for (int jt = 0; jt < 4; ++jt) {
      int row = jt * 16 + lr;
#pragma unroll
      for (int kk = 0; kk < 2; ++kk) {
        int cc = (kk * 4 + lg) ^ (row & 7);
        bf16x8 kf = *(const bf16x8*)(Ks + row * 64 + cc * 8);
#pragma unroll
        for (int it = 0; it < 2; ++it)
          accs[jt][it] = __builtin_amdgcn_mfma_f32_16x16x32_bf16(kf, qf[it][kk], accs[jt][it], 0, 0, 0);
      }
#pragma unroll
      for (int kk = 0; kk < 2; ++kk) {
        int cc = (kk * 4 + lg) ^ (row & 7);
        bf16x8 qsf = *(const bf16x8*)(Qs + row * 64 + cc * 8);
#pragma unroll
        for (int it = 0; it < 2; ++it)
          accs[jt][it] = __builtin_amdgcn_mfma_f32_16x16x32_bf16(qsf, kreg[it][kk], accs[jt][it], 0, 0, 0);
      }
    }
    __builtin_amdgcn_s_setprio(0);

    __syncthreads();   // all waves done reading Ks/Qs -> safe to overwrite (drain lands V(kt+1))
    if (kt < 15) STAGE_KQ(kt + 1);   // lands during softmax+PV below

    // ---- p = exp2(C2 * rcp(exp2(acc)+1)); truncate to bf16 (pack_hi16) ----
#pragma unroll
    for (int jt = 0; jt < 4; ++jt) {
      const int ks = jt >> 1, jtl = jt & 1;
#pragma unroll
      for (int it = 0; it < 2; ++it) {
        float p0 = exp2_fast(C2 * __builtin_amdgcn_rcpf(exp2_fast(accs[jt][it][0]) + 1.0f));
        float p1 = exp2_fast(C2 * __builtin_amdgcn_rcpf(exp2_fast(accs[jt][it][1]) + 1.0f));
        float p2 = exp2_fast(C2 * __builtin_amdgcn_rcpf(exp2_fast(accs[jt][it][2]) + 1.0f));
        float p3 = exp2_fast(C2 * __builtin_amdgcn_rcpf(exp2_fast(accs[jt][it][3]) + 1.0f));
        uint2 w;
        w.x = pack_hi16(f2bits(p0), f2bits(p1));
        w.y = pack_hi16(f2bits(p2), f2bits(p3));
        *(uint2*)(&Ps[wv][ks][(it * 16 + lr) * 40 + jtl * 16 + lg * 4]) = w;
      }
    }

    // forbid compiler from reordering the P reads above the P writes
    asm volatile("" ::: "memory");

    // ---- O^T += mfma(V-frag, P-frag); denominator += mfma(ones, P-frag) ----
    {
      const u16* V0 = Vs[cur];
#pragma unroll
      for (int ks = 0; ks < 2; ++ks) {
        bf16x8 pa[2];
#pragma unroll
        for (int it = 0; it < 2; ++it)
          pa[it] = *(const bf16x8*)(&Ps[wv][ks][(it * 16 + lr) * 40 + lg * 8]);
        __builtin_amdgcn_s_setprio(1);
#pragma unroll
        for (int dt = 0; dt < 4; ++dt) {
          int row  = dt * 16 + lr;
          int slot = (ks * 4 + lg) ^ (lr & 7);
          bf16x8 vf = *(const bf16x8*)(V0 + row * 64 + slot * 8);
#pragma unroll
          for (int it = 0; it < 2; ++it)
            acc_o[dt][it] = __builtin_amdgcn_mfma_f32_16x16x32_bf16(vf, pa[it], acc_o[dt][it], 0, 0, 0);
        }
#pragma unroll
        for (int it = 0; it < 2; ++it)
          acc_sum[it] = __builtin_amdgcn_mfma_f32_16x16x32_bf16(ones8, pa[it], acc_sum[it], 0, 0, 0);
        __builtin_amdgcn_s_setprio(0);
      }
    }
  }
#undef STAGE_KQ
#undef STAGE_V

  // ---- denominator: every lane already holds its token's sum (col = lr); invert ----
  float rinv[2];
#pragma unroll
  for (int it = 0; it < 2; ++it)
    rinv[it] = __builtin_amdgcn_rcpf(acc_sum[it][0]);

  // ---- write O: token n = qb*128+wv*32+it*16+lr ; feature = h*64 + dt*16 + lg*4 + r ----
#pragma unroll
  for (int dt = 0; dt < 4; ++dt) {
#pragma unroll
    for (int it = 0; it < 2; ++it) {
      float v0 = acc_o[dt][it][0] * rinv[it];
      float v1 = acc_o[dt][it][1] * rinv[it];
      float v2 = acc_o[dt][it][2] * rinv[it];
      float v3 = acc_o[dt][it][3] * rinv[it];
      uint2 w;
      w.x = (uint32_t)f2bf(v0) | ((uint32_t)f2bf(v1) << 16);
      w.y = (uint32_t)f2bf(v2) | ((uint32_t)f2bf(v3) << 16);
      int n = qb * 128 + wv * 32 + it * 16 + lr;
      *(uint2*)(attn + ((size_t)(b * 1024 + n)) * 768 + h * 64 + dt * 16 + lg * 4) = w;
    }
  }
}

// ---------------- GEMM2: output projection (fp32 out, coalesced scalar stores) ----------------
__global__ __launch_bounds__(256) void k_gemm_proj(
    const u16* __restrict__ Ain, const u16* __restrict__ Bw, const float* __restrict__ bias,
    float* __restrict__ out) {
  __shared__ u16 As[2 * 128 * 32];
  __shared__ u16 Bs[2 * 128 * 32];
  int bid = blockIdx.x;
  int wg  = (bid & 7) * 48 + (bid >> 3);
  int bx  = wg % 6, by = wg / 6;

  f32x4 acc[4][4];
#pragma unroll
  for (int mi = 0; mi < 4; ++mi)
#pragma unroll
    for (int ni = 0; ni < 4; ++ni) acc[mi][ni] = (f32x4){0.f, 0.f, 0.f, 0.f};

  gemm_core<false>(Ain, Bw, As, Bs, by * 128, bx * 128, acc);

  const int t = threadIdx.x, lane = t & 63, wv = t >> 6;
  const int wr = wv >> 1, wc = wv & 1, lr = lane & 15, lg = lane >> 4;
  const int col0 = bx * 128 + wc * 64;

  float bv[4];
#pragma unroll
  for (int ni = 0; ni < 4; ++ni) bv[ni] = bias[col0 + ni * 16 + lr];

#pragma unroll
  for (int mi = 0; mi < 4; ++mi) {
    int tok0 = by * 128 + wr * 64 + mi * 16 + lg * 4;
#pragma unroll
    for (int ni = 0; ni < 4; ++ni) {
      int col = col0 + ni * 16 + lr;
#pragma unroll
      for (int r = 0; r < 4; ++r) {
        out[(size_t)(tok0 + r) * 768 + col] = acc[mi][ni][r] + bv[ni];
      }
    }
  }
}

// ---------------- launch ----------------
extern "C" void kernel_launch(void* const* d_in, const int* in_sizes, int n_in,
                              void* d_out, int out_size, void* d_ws, size_t ws_size,
                              hipStream_t stream) {
  (void)in_sizes; (void)n_in; (void)out_size;
  const float* x      = (const float*)d_in[0];
  const float* qkv_w  = (const float*)d_in[1];
  const float* qkv_b  = (const float*)d_in[2];
  const float* proj_w = (const float*)d_in[3];
  const float* proj_b = (const float*)d_in[4];
  float* out = (float*)d_out;

  uint8_t* ws = (uint8_t*)d_ws;
  u16* xb  = (u16*)(ws + 0);          // 8192*768  bf16 (reused as attn_out)
  u16* wqb = (u16*)(ws + 12582912);
  u16* wpb = (u16*)(ws + 16121856);
  u16* Qh  = (u16*)(ws + 17301504);   // 96*1024*64 bf16 = 12.58 MB  (Q* = sc1*q)
  u16* Kh  = (u16*)(ws + 42467328);   // 96*1024*64 bf16 = 12.58 MB  (K* = sc1*k)
  u16* Vt  = (u16*)(ws + 80216064);   // [bh][d][n] written directly by k_gemm_qkv
  if (ws_size < 92798976) return;

  u16* attnb = xb;

  k_convert<<<2048, 256, 0, stream>>>(x, qkv_w, proj_w, xb, wqb, wpb);
  k_gemm_qkv<<<1152, 256, 0, stream>>>(xb, wqb, qkv_b, Qh, Kh, Vt);
  k_attn<<<768, 256, 0, stream>>>(Qh, Kh, Vt, attnb);
  k_gemm_proj<<<384, 256, 0, stream>>>(attnb, wpb, proj_b, out);
}